// Round 22
// baseline (171.107 us; speedup 1.0000x reference)
//
#include <hip/hip_runtime.h>
#include <hip/hip_bf16.h>
#include <cstdint>
#include <cstddef>

// Problem shape (fixed): x [B=16][N=2048][D=512] fp32
#define BB 16
#define NN 2048
#define DD 512

typedef _Float16 f16x8 __attribute__((ext_vector_type(8)));
typedef _Float16 f16x4 __attribute__((ext_vector_type(4)));
typedef float f32x4 __attribute__((ext_vector_type(4)));
typedef unsigned int u32x4 __attribute__((ext_vector_type(4)));

// Async global->LDS, 16 B per lane. LDS dest = wave-uniform base + lane*16.
__device__ __forceinline__ void async_ld16(void* lds, const void* g) {
    __builtin_amdgcn_global_load_lds(
        (const __attribute__((address_space(1))) unsigned int*)(uintptr_t)g,
        (__attribute__((address_space(3))) unsigned int*)(uint32_t)(uintptr_t)lds,
        16, 0, 0);
}

#define VM_WAIT(n) asm volatile("s_waitcnt vmcnt(" #n ")" ::: "memory")
#define RAW_BAR()  do { asm volatile("" ::: "memory"); __builtin_amdgcn_s_barrier(); asm volatile("" ::: "memory"); } while (0)
// LDS-order-only barrier: global stores/atomics keep draining.
#define LGKM_BAR() do { asm volatile("s_waitcnt lgkmcnt(0)" ::: "memory"); \
                        __builtin_amdgcn_s_barrier();                      \
                        __builtin_amdgcn_sched_barrier(0); } while (0)

// ---------------------------------------------------------------------------
// K1 (fused): read x ONCE (non-temporal: stream-once). Per 64-row slab:
// norms, xhn (normalized fp16), vT (fp16 transpose), denom zero-init.
// grid (NN/64, BB), 256 threads.
// ---------------------------------------------------------------------------
__global__ __launch_bounds__(256) void k_prep(const float* __restrict__ x,
                                              _Float16* __restrict__ xhn,
                                              _Float16* __restrict__ vT,
                                              float* __restrict__ denom) {
    __shared__ _Float16 t[512 * 66];     // [d][j], pitch 66 halves
    const int tid = threadIdx.x, lane = tid & 63, w = tid >> 6;
    const int b = blockIdx.y, j0 = blockIdx.x * 64;
    if (tid < 64) denom[b * NN + j0 + tid] = 0.f;
    const float* xb = x + ((size_t)b * NN + j0) * DD;

    for (int rr = 0; rr < 16; ++rr) {
        const int jj = w * 16 + rr;                 // row within slab
        const float* xr = xb + (size_t)jj * DD;
        f32x4 a = __builtin_nontemporal_load((const f32x4*)xr + lane);
        f32x4 c = __builtin_nontemporal_load((const f32x4*)xr + lane + 64);
        float ss = a[0]*a[0] + a[1]*a[1] + a[2]*a[2] + a[3]*a[3]
                 + c[0]*c[0] + c[1]*c[1] + c[2]*c[2] + c[3]*c[3];
        #pragma unroll
        for (int o = 1; o < 64; o <<= 1) ss += __shfl_xor(ss, o);
        const float rn = 1.0f / sqrtf(ss);
        // normalized fp16 row (coalesced 8B stores)
        _Float16* dst = xhn + ((size_t)b * NN + j0 + jj) * DD;
        f16x4 v0 = {(_Float16)(a[0]*rn), (_Float16)(a[1]*rn), (_Float16)(a[2]*rn), (_Float16)(a[3]*rn)};
        f16x4 v1 = {(_Float16)(c[0]*rn), (_Float16)(c[1]*rn), (_Float16)(c[2]*rn), (_Float16)(c[3]*rn)};
        *(f16x4*)(dst + 4 * lane) = v0;
        *(f16x4*)(dst + 256 + 4 * lane) = v1;
        // unnormalized fp16 into transposed LDS tile
        const int d0 = 4 * lane, d1 = 256 + 4 * lane;
        t[(d0 + 0) * 66 + jj] = (_Float16)a[0];
        t[(d0 + 1) * 66 + jj] = (_Float16)a[1];
        t[(d0 + 2) * 66 + jj] = (_Float16)a[2];
        t[(d0 + 3) * 66 + jj] = (_Float16)a[3];
        t[(d1 + 0) * 66 + jj] = (_Float16)c[0];
        t[(d1 + 1) * 66 + jj] = (_Float16)c[1];
        t[(d1 + 2) * 66 + jj] = (_Float16)c[2];
        t[(d1 + 3) * 66 + jj] = (_Float16)c[3];
    }
    LGKM_BAR();   // xhn global stores keep draining under the vT phase
    // store vT rows: 512 d x 8 chunks of 8 halves; 4B-aligned b32 LDS reads.
    #pragma unroll
    for (int it = 0; it < 16; ++it) {
        const int id = it * 256 + tid;
        const int d = id >> 3, ch = (id & 7) * 8;
        const uint32_t* tp = (const uint32_t*)&t[d * 66 + ch];
        uint4 v = {tp[0], tp[1], tp[2], tp[3]};
        *(uint4*)(vT + ((size_t)b * DD + d) * NN + j0 + ch) = v;
    }
}

// ---------------------------------------------------------------------------
// K2: W = exp( xhn xhn^T ), symmetric-triangular. 128x128 block, 4 waves.
// BK=32 RING-2 double buffer (2 x 16 KiB) with COUNTED vmcnt(4) — the
// untested combination of R2's counted-vmcnt (+8 us at 2 blk/CU) and R7's
// 4 blocks/CU (+2.4 us, single-buffer). Declared LDS stays 34816 B (epi
// scratch dominates) -> still 4 blocks/CU.
// 16 K-steps: {VM_WAIT(4) -> bar -> 8 ds_read + 16 mfma -> bar ->
// stage(kb+2) 4 loads}. VM_WAIT(0) only at the last step.
// Epilogue unchanged from R19 (stores-before-atomics, LGKM-only barriers).
// ---------------------------------------------------------------------------
__global__ __launch_bounds__(256, 4) void k_scores(const _Float16* __restrict__ xhn,
                                                   _Float16* __restrict__ W,
                                                   float* __restrict__ denom) {
    __shared__ _Float16 smem[17408];          // 2 x 8192 GEMM bufs; epi: 128x136
    const int tid = threadIdx.x;
    const int lane = tid & 63, wv = tid >> 6;
    const int wr = wv >> 1, wc = wv & 1;
    const int m_ = lane & 15, quad = lane >> 4;
    const int b = blockIdx.z;

    // XCD swizzle: 136 = 8 * 17 -> each XCD gets 17 consecutive pairs.
    const int swz = (blockIdx.x % 8) * 17 + blockIdx.x / 8;
    int rem = swz, ti = 0, rowlen = NN / 128;
    while (rem >= rowlen) { rem -= rowlen; ++ti; --rowlen; }
    const int tj = ti + rem;
    const int I = ti * 128, J = tj * 128;
    const bool diag = (ti == tj);

    const _Float16* Ab = xhn + ((size_t)b * NN + I) * DD;
    const _Float16* Bb = xhn + ((size_t)b * NN + J) * DD;

    f32x4 acc[4][4];
    #pragma unroll
    for (int i = 0; i < 4; ++i)
        #pragma unroll
        for (int j = 0; j < 4; ++j) acc[i][j] = (f32x4){0.f, 0.f, 0.f, 0.f};

    // Staging geometry (BK=32, 64 B rows): lane covers row wv*16 + (lane>>2),
    // 16B chunk lane&3; source chunk pre-swizzled by (row&3) (both-sides).
    const int srw = lane >> 2;                // row within 16-row wave group
    const int sck = lane & 3;                 // 16B chunk
    const int soff = ((sck ^ ((srw) & 3)) * 8);   // halves
    const _Float16* agl = Ab + (size_t)(wv * 16 + srw) * DD + soff;
    const _Float16* bgl = Bb + (size_t)(wv * 16 + srw) * DD + soff;

// Stage tile kb_ (4 vmem loads: A rows 0-63, A rows 64-127, B same).
#define S_STG(kb_) do {                                                       \
    _Float16* A_ = smem + (((kb_) & 1) << 13);   /* buf = kb&1, 8192 halves */\
    const int k0_ = (kb_) * 32;                                               \
    async_ld16(&A_[(wv * 16) * 32],             agl + k0_);                   \
    async_ld16(&A_[(64 + wv * 16) * 32],        agl + (size_t)64 * DD + k0_); \
    async_ld16(&A_[4096 + (wv * 16) * 32],      bgl + k0_);                   \
    async_ld16(&A_[4096 + (64 + wv * 16) * 32], bgl + (size_t)64 * DD + k0_); \
    } while (0)

    S_STG(0); S_STG(1);
    for (int kb = 0; kb < DD / 32; ++kb) {
        if (kb == DD / 32 - 1) { VM_WAIT(0); } else { VM_WAIT(4); }
        RAW_BAR();
        const _Float16* As_ = smem + ((kb & 1) << 13);
        const _Float16* Bs_ = As_ + 4096;
        __builtin_amdgcn_s_setprio(1);
        {
            f16x8 af[4], bf[4];
            #pragma unroll
            for (int t = 0; t < 4; ++t) {
                const int Ra = wr * 64 + t * 16 + m_;
                const int Rb = wc * 64 + t * 16 + m_;
                af[t] = *(const f16x8*)&As_[Ra * 32 + ((quad ^ (Ra & 3)) * 8)];
                bf[t] = *(const f16x8*)&Bs_[Rb * 32 + ((quad ^ (Rb & 3)) * 8)];
            }
            #pragma unroll
            for (int i = 0; i < 4; ++i)
                #pragma unroll
                for (int j = 0; j < 4; ++j)
                    acc[i][j] = __builtin_amdgcn_mfma_f32_16x16x32_f16(af[i], bf[j], acc[i][j], 0, 0, 0);
        }
        __builtin_amdgcn_s_setprio(0);
        RAW_BAR();   // all waves done reading buf before stage(kb+2) overwrites
        if (kb + 2 < DD / 32) S_STG(kb + 2);
    }
#undef S_STG

    // Epilogue: exp into packed f16x4; register row/col partial sums.
    f16x4 wq[4][4];
    float rowpart[4][4];
    float colpart[4] = {0.f, 0.f, 0.f, 0.f};
    #pragma unroll
    for (int i = 0; i < 4; ++i)
        #pragma unroll
        for (int r = 0; r < 4; ++r) rowpart[i][r] = 0.f;

    #pragma unroll
    for (int i = 0; i < 4; ++i) {
        #pragma unroll
        for (int j = 0; j < 4; ++j) {
            #pragma unroll
            for (int r = 0; r < 4; ++r) {
                const float w = __expf(acc[i][j][r]);
                wq[i][j][r] = (_Float16)w;
                rowpart[i][r] += w;
                colpart[j] += w;
            }
        }
    }

    // Phase 1 FIRST: WtT[col][row] (stride 136) -> coalesced W(J,I) stores.
    _Float16* WtT = smem;
    #pragma unroll
    for (int i = 0; i < 4; ++i) {
        const int rowb = wr * 64 + i * 16 + quad * 4;
        #pragma unroll
        for (int j = 0; j < 4; ++j) {
            const int col = wc * 64 + j * 16 + m_;
            *(f16x4*)&WtT[col * 136 + rowb] = wq[i][j];
        }
    }
    LGKM_BAR();
    // lane-coalesced store: 16 lanes = one contiguous 256 B row segment.
    #pragma unroll
    for (int it2 = 0; it2 < 8; ++it2) {
        const int id = it2 * 256 + tid;
        const int rr = id >> 4, off = (id & 15) * 8;
        *(uint4*)(W + ((size_t)b * NN + J + rr) * NN + I + off) =
            *(const uint4*)&WtT[rr * 136 + off];
    }

    // Denom butterflies + atomics WHILE the W(J,I) store stream drains.
    #pragma unroll
    for (int i = 0; i < 4; ++i) {
        #pragma unroll
        for (int r = 0; r < 4; ++r) {
            float s = rowpart[i][r];
            s += __shfl_xor(s, 1);
            s += __shfl_xor(s, 2);
            s += __shfl_xor(s, 4);
            s += __shfl_xor(s, 8);
            if (m_ == 0)
                atomicAdd(&denom[b * NN + I + wr * 64 + i * 16 + quad * 4 + r], s);
        }
    }
    if (!diag) {
        #pragma unroll
        for (int j = 0; j < 4; ++j) {
            float s = colpart[j];
            s += __shfl_xor(s, 16);
            s += __shfl_xor(s, 32);
            if (quad == 0)
                atomicAdd(&denom[b * NN + J + wc * 64 + j * 16 + m_], s);
        }
    }

    // Phase 2 (off-diag): row-major Wt -> coalesced W(I,J).
    if (!diag) {
        LGKM_BAR();   // phase-1 LDS reads done; stores/atomics still in flight
        _Float16* Wt = smem;
        #pragma unroll
        for (int i = 0; i < 4; ++i) {
            const int rowb = wr * 64 + i * 16 + quad * 4;
            #pragma unroll
            for (int j = 0; j < 4; ++j) {
                const int col = wc * 64 + j * 16 + m_;
                #pragma unroll
                for (int r = 0; r < 4; ++r)
                    Wt[(rowb + r) * 136 + col] = wq[i][j][r];
            }
        }
        LGKM_BAR();
        #pragma unroll
        for (int it2 = 0; it2 < 8; ++it2) {
            const int id = it2 * 256 + tid;
            const int rr = id >> 4, off = (id & 15) * 8;
            *(uint4*)(W + ((size_t)b * NN + I + rr) * NN + J + off) =
                *(const uint4*)&Wt[rr * 136 + off];
        }
    }
}

// ---------------------------------------------------------------------------
// K3 (R19 exact, unchanged): O = (W @ V) * (1/denom_i), fp32 out.
// 128x128 tile, 4-wave blocks, single-buffer 32.5 KiB LDS -> 4 blocks/CU,
// grid 1024 = 4 full rounds. W staging cached (L3-resident); out stores NT;
// XCD batch-pinned, 4 D-blocks of a W row-panel on adjacent same-XCD slots;
// denom load hoisted above the K-loop.
// ---------------------------------------------------------------------------
__global__ __launch_bounds__(256, 4) void k_pv(const _Float16* __restrict__ W,
                                               const _Float16* __restrict__ vT,
                                               const float* __restrict__ denom,
                                               float* __restrict__ out) {
    __shared__ _Float16 As[8192];      // [128][64]
    __shared__ _Float16 Bs[8192];      // [128][64]
    __shared__ float rdI[128];
    const int tid = threadIdx.x;
    const int lane = tid & 63, w = tid >> 6;  // 4 waves
    const int wr = w >> 1, wc = w & 1;        // 2 x 2 wave grid
    const int m_ = lane & 15, quad = lane >> 4;

    // XCD pinning: 1024 blocks, 128 slots/XCD, 2 batches/XCD.
    const int bx = blockIdx.x;
    const int xcd = bx & 7, slot = bx >> 3;        // slot 0..127
    const int b  = (slot >> 6) * 8 + xcd;          // 2 batches/XCD
    const int r_ = slot & 63;                      // 64 blocks/batch
    const int I  = (r_ >> 2) * 128;                // 16 I-tiles
    const int D0 = (r_ & 3) * 128;                 // 4 D-blocks adjacent

    // Hoisted denom load: latency hides under the entire K-loop.
    float dv = 0.f;
    if (tid < 128) dv = denom[b * NN + I + tid];

    const _Float16* Ab = W  + ((size_t)b * NN + I) * NN;
    const _Float16* Bb = vT + ((size_t)b * DD + D0) * NN;

    const int sub = lane >> 3;
    const int swc = (lane & 7) ^ sub;
    // A: 128 rows, wave stages 32 rows (4 chunks of 8). B: same.
    const _Float16* agl = Ab + (size_t)(w * 32 + sub) * NN + swc * 8;
    const _Float16* bgl = Bb + (size_t)(w * 32 + sub) * NN + swc * 8;

    f32x4 acc[4][4];
    #pragma unroll
    for (int i = 0; i < 4; ++i)
        #pragma unroll
        for (int j = 0; j < 4; ++j) acc[i][j] = (f32x4){0.f, 0.f, 0.f, 0.f};

    for (int kb = 0; kb < NN / 64; ++kb) {
        const int k0 = kb * 64;
        #pragma unroll
        for (int c = 0; c < 4; ++c) {
            async_ld16(&As[(w * 32 + c * 8) * 64], agl + (size_t)c * 8 * NN + k0);
            async_ld16(&Bs[(w * 32 + c * 8) * 64], bgl + (size_t)c * 8 * NN + k0);
        }
        VM_WAIT(0);
        RAW_BAR();
        __builtin_amdgcn_s_setprio(1);
        #pragma unroll
        for (int kc = 0; kc < 2; ++kc) {
            f16x8 af[4], bf[4];
            #pragma unroll
            for (int t = 0; t < 4; ++t) {
                const int Ra = wr * 64 + t * 16 + m_;
                const int Rb = wc * 64 + t * 16 + m_;
                af[t] = *(const f16x8*)&As[Ra * 64 + (((kc * 4 + quad) ^ (Ra & 7)) * 8)];
                bf[t] = *(const f16x8*)&Bs[Rb * 64 + (((kc * 4 + quad) ^ (Rb & 7)) * 8)];
            }
            #pragma unroll
            for (int i = 0; i < 4; ++i)
                #pragma unroll
                for (int j = 0; j < 4; ++j)
                    acc[i][j] = __builtin_amdgcn_mfma_f32_16x16x32_f16(af[i], bf[j], acc[i][j], 0, 0, 0);
        }
        __builtin_amdgcn_s_setprio(0);
        RAW_BAR();   // all waves done reading before next stage overwrites
    }

    // Epilogue: broadcast reciprocals via LDS, NT stores.
    if (tid < 128) rdI[tid] = 1.0f / dv;
    LGKM_BAR();

    #pragma unroll
    for (int i = 0; i < 4; ++i) {
        const int rowb = wr * 64 + i * 16 + quad * 4;
        #pragma unroll
        for (int r = 0; r < 4; ++r) {
            const float sc = rdI[rowb + r];
            float* op = out + ((size_t)(b * NN + I + rowb + r)) * DD + D0;
            #pragma unroll
            for (int j = 0; j < 4; ++j)
                __builtin_nontemporal_store(acc[i][j][r] * sc,
                                            op + wc * 64 + j * 16 + m_);
        }
    }
}

// ---------------------------------------------------------------------------
extern "C" void kernel_launch(void* const* d_in, const int* in_sizes, int n_in,
                              void* d_out, int out_size, void* d_ws, size_t ws_size,
                              hipStream_t stream) {
    const float* x = (const float*)d_in[0];
    char* ws = (char*)d_ws;
    _Float16* xhn   = (_Float16*)(ws);                        // 32 MiB normalized fp16
    _Float16* vT    = (_Float16*)(ws + (size_t)33554432);     // 32 MiB fp16 x^T
    _Float16* W     = (_Float16*)(ws + (size_t)67108864);     // 128 MiB fp16 exp-scores
    float*    denom = (float*)   (ws + (size_t)201326592);    // 128 KiB
    float*    out   = (float*)d_out;

    k_prep<<<dim3(NN / 64, BB), 256, 0, stream>>>(x, xhn, vT, denom);
    const int npairs = (NN / 128) * (NN / 128 + 1) / 2;   // 136
    k_scores<<<dim3(npairs, 1, BB), 256, 0, stream>>>(xhn, W, denom);
    // 1024 blocks = 4 blocks/CU (32.5 KiB LDS, 4-wave blocks), XCD batch-pinned
    k_pv<<<dim3(1024, 1, 1), 256, 0, stream>>>(W, vT, denom, out);
}

// Round 23
// 170.793 us; speedup vs baseline: 1.0018x; 1.0018x over previous
//
#include <hip/hip_runtime.h>
#include <hip/hip_bf16.h>
#include <cstdint>
#include <cstddef>

// Problem shape (fixed): x [B=16][N=2048][D=512] fp32
#define BB 16
#define NN 2048
#define DD 512

typedef _Float16 f16x8 __attribute__((ext_vector_type(8)));
typedef _Float16 f16x4 __attribute__((ext_vector_type(4)));
typedef float f32x4 __attribute__((ext_vector_type(4)));
typedef unsigned int u32x4 __attribute__((ext_vector_type(4)));

// Async global->LDS, 16 B per lane. LDS dest = wave-uniform base + lane*16.
__device__ __forceinline__ void async_ld16(void* lds, const void* g) {
    __builtin_amdgcn_global_load_lds(
        (const __attribute__((address_space(1))) unsigned int*)(uintptr_t)g,
        (__attribute__((address_space(3))) unsigned int*)(uint32_t)(uintptr_t)lds,
        16, 0, 0);
}

#define VM_WAIT(n) asm volatile("s_waitcnt vmcnt(" #n ")" ::: "memory")
#define RAW_BAR()  do { asm volatile("" ::: "memory"); __builtin_amdgcn_s_barrier(); asm volatile("" ::: "memory"); } while (0)
// LDS-order-only barrier: global stores/atomics keep draining.
#define LGKM_BAR() do { asm volatile("s_waitcnt lgkmcnt(0)" ::: "memory"); \
                        __builtin_amdgcn_s_barrier();                      \
                        __builtin_amdgcn_sched_barrier(0); } while (0)

// ---------------------------------------------------------------------------
// K1 (fused): read x ONCE (non-temporal: stream-once). Per 64-row slab:
// norms, xhn (normalized fp16), vT (fp16 transpose), denom zero-init.
// grid (NN/64, BB), 256 threads.
// ---------------------------------------------------------------------------
__global__ __launch_bounds__(256) void k_prep(const float* __restrict__ x,
                                              _Float16* __restrict__ xhn,
                                              _Float16* __restrict__ vT,
                                              float* __restrict__ denom) {
    __shared__ _Float16 t[512 * 66];     // [d][j], pitch 66 halves
    const int tid = threadIdx.x, lane = tid & 63, w = tid >> 6;
    const int b = blockIdx.y, j0 = blockIdx.x * 64;
    if (tid < 64) denom[b * NN + j0 + tid] = 0.f;
    const float* xb = x + ((size_t)b * NN + j0) * DD;

    for (int rr = 0; rr < 16; ++rr) {
        const int jj = w * 16 + rr;                 // row within slab
        const float* xr = xb + (size_t)jj * DD;
        f32x4 a = __builtin_nontemporal_load((const f32x4*)xr + lane);
        f32x4 c = __builtin_nontemporal_load((const f32x4*)xr + lane + 64);
        float ss = a[0]*a[0] + a[1]*a[1] + a[2]*a[2] + a[3]*a[3]
                 + c[0]*c[0] + c[1]*c[1] + c[2]*c[2] + c[3]*c[3];
        #pragma unroll
        for (int o = 1; o < 64; o <<= 1) ss += __shfl_xor(ss, o);
        const float rn = 1.0f / sqrtf(ss);
        // normalized fp16 row (coalesced 8B stores)
        _Float16* dst = xhn + ((size_t)b * NN + j0 + jj) * DD;
        f16x4 v0 = {(_Float16)(a[0]*rn), (_Float16)(a[1]*rn), (_Float16)(a[2]*rn), (_Float16)(a[3]*rn)};
        f16x4 v1 = {(_Float16)(c[0]*rn), (_Float16)(c[1]*rn), (_Float16)(c[2]*rn), (_Float16)(c[3]*rn)};
        *(f16x4*)(dst + 4 * lane) = v0;
        *(f16x4*)(dst + 256 + 4 * lane) = v1;
        // unnormalized fp16 into transposed LDS tile
        const int d0 = 4 * lane, d1 = 256 + 4 * lane;
        t[(d0 + 0) * 66 + jj] = (_Float16)a[0];
        t[(d0 + 1) * 66 + jj] = (_Float16)a[1];
        t[(d0 + 2) * 66 + jj] = (_Float16)a[2];
        t[(d0 + 3) * 66 + jj] = (_Float16)a[3];
        t[(d1 + 0) * 66 + jj] = (_Float16)c[0];
        t[(d1 + 1) * 66 + jj] = (_Float16)c[1];
        t[(d1 + 2) * 66 + jj] = (_Float16)c[2];
        t[(d1 + 3) * 66 + jj] = (_Float16)c[3];
    }
    LGKM_BAR();   // xhn global stores keep draining under the vT phase
    // store vT rows: 512 d x 8 chunks of 8 halves; 4B-aligned b32 LDS reads.
    #pragma unroll
    for (int it = 0; it < 16; ++it) {
        const int id = it * 256 + tid;
        const int d = id >> 3, ch = (id & 7) * 8;
        const uint32_t* tp = (const uint32_t*)&t[d * 66 + ch];
        uint4 v = {tp[0], tp[1], tp[2], tp[3]};
        *(uint4*)(vT + ((size_t)b * DD + d) * NN + j0 + ch) = v;
    }
}

// ---------------------------------------------------------------------------
// K2: W = exp( xhn xhn^T ), symmetric-triangular. 128x128 block, 4 waves.
// BK=32 RING-2 double buffer (2 x 16 KiB) with COUNTED vmcnt(4) — R22
// measured k_scores 75.5 -> 72.3-73.3 us (R2's counted-vmcnt composed with
// R7's 4 blocks/CU). Declared LDS stays 34816 B -> 4 blocks/CU.
// 16 K-steps: {VM_WAIT(4) -> bar -> 8 ds_read + 16 mfma -> bar ->
// stage(kb+2) 4 loads}. VM_WAIT(0) only at the last step.
// Epilogue: stores-before-atomics, LGKM-only barriers, lane-coalesced stores.
// ---------------------------------------------------------------------------
__global__ __launch_bounds__(256, 4) void k_scores(const _Float16* __restrict__ xhn,
                                                   _Float16* __restrict__ W,
                                                   float* __restrict__ denom) {
    __shared__ _Float16 smem[17408];          // 2 x 8192 GEMM bufs; epi: 128x136
    const int tid = threadIdx.x;
    const int lane = tid & 63, wv = tid >> 6;
    const int wr = wv >> 1, wc = wv & 1;
    const int m_ = lane & 15, quad = lane >> 4;
    const int b = blockIdx.z;

    // XCD swizzle: 136 = 8 * 17 -> each XCD gets 17 consecutive pairs.
    const int swz = (blockIdx.x % 8) * 17 + blockIdx.x / 8;
    int rem = swz, ti = 0, rowlen = NN / 128;
    while (rem >= rowlen) { rem -= rowlen; ++ti; --rowlen; }
    const int tj = ti + rem;
    const int I = ti * 128, J = tj * 128;
    const bool diag = (ti == tj);

    const _Float16* Ab = xhn + ((size_t)b * NN + I) * DD;
    const _Float16* Bb = xhn + ((size_t)b * NN + J) * DD;

    f32x4 acc[4][4];
    #pragma unroll
    for (int i = 0; i < 4; ++i)
        #pragma unroll
        for (int j = 0; j < 4; ++j) acc[i][j] = (f32x4){0.f, 0.f, 0.f, 0.f};

    // Staging geometry (BK=32, 64 B rows): lane covers row wv*16 + (lane>>2),
    // 16B chunk lane&3; source chunk pre-swizzled by (row&3) (both-sides).
    const int srw = lane >> 2;                // row within 16-row wave group
    const int sck = lane & 3;                 // 16B chunk
    const int soff = ((sck ^ ((srw) & 3)) * 8);   // halves
    const _Float16* agl = Ab + (size_t)(wv * 16 + srw) * DD + soff;
    const _Float16* bgl = Bb + (size_t)(wv * 16 + srw) * DD + soff;

// Stage tile kb_ (4 vmem loads: A rows 0-63, A rows 64-127, B same).
#define S_STG(kb_) do {                                                       \
    _Float16* A_ = smem + (((kb_) & 1) << 13);   /* buf = kb&1, 8192 halves */\
    const int k0_ = (kb_) * 32;                                               \
    async_ld16(&A_[(wv * 16) * 32],             agl + k0_);                   \
    async_ld16(&A_[(64 + wv * 16) * 32],        agl + (size_t)64 * DD + k0_); \
    async_ld16(&A_[4096 + (wv * 16) * 32],      bgl + k0_);                   \
    async_ld16(&A_[4096 + (64 + wv * 16) * 32], bgl + (size_t)64 * DD + k0_); \
    } while (0)

    S_STG(0); S_STG(1);
    for (int kb = 0; kb < DD / 32; ++kb) {
        if (kb == DD / 32 - 1) { VM_WAIT(0); } else { VM_WAIT(4); }
        RAW_BAR();
        const _Float16* As_ = smem + ((kb & 1) << 13);
        const _Float16* Bs_ = As_ + 4096;
        __builtin_amdgcn_s_setprio(1);
        {
            f16x8 af[4], bf[4];
            #pragma unroll
            for (int t = 0; t < 4; ++t) {
                const int Ra = wr * 64 + t * 16 + m_;
                const int Rb = wc * 64 + t * 16 + m_;
                af[t] = *(const f16x8*)&As_[Ra * 32 + ((quad ^ (Ra & 3)) * 8)];
                bf[t] = *(const f16x8*)&Bs_[Rb * 32 + ((quad ^ (Rb & 3)) * 8)];
            }
            #pragma unroll
            for (int i = 0; i < 4; ++i)
                #pragma unroll
                for (int j = 0; j < 4; ++j)
                    acc[i][j] = __builtin_amdgcn_mfma_f32_16x16x32_f16(af[i], bf[j], acc[i][j], 0, 0, 0);
        }
        __builtin_amdgcn_s_setprio(0);
        RAW_BAR();   // all waves done reading buf before stage(kb+2) overwrites
        if (kb + 2 < DD / 32) S_STG(kb + 2);
    }
#undef S_STG

    // Epilogue: exp into packed f16x4; register row/col partial sums.
    f16x4 wq[4][4];
    float rowpart[4][4];
    float colpart[4] = {0.f, 0.f, 0.f, 0.f};
    #pragma unroll
    for (int i = 0; i < 4; ++i)
        #pragma unroll
        for (int r = 0; r < 4; ++r) rowpart[i][r] = 0.f;

    #pragma unroll
    for (int i = 0; i < 4; ++i) {
        #pragma unroll
        for (int j = 0; j < 4; ++j) {
            #pragma unroll
            for (int r = 0; r < 4; ++r) {
                const float w = __expf(acc[i][j][r]);
                wq[i][j][r] = (_Float16)w;
                rowpart[i][r] += w;
                colpart[j] += w;
            }
        }
    }

    // Phase 1 FIRST: WtT[col][row] (stride 136) -> coalesced W(J,I) stores.
    _Float16* WtT = smem;
    #pragma unroll
    for (int i = 0; i < 4; ++i) {
        const int rowb = wr * 64 + i * 16 + quad * 4;
        #pragma unroll
        for (int j = 0; j < 4; ++j) {
            const int col = wc * 64 + j * 16 + m_;
            *(f16x4*)&WtT[col * 136 + rowb] = wq[i][j];
        }
    }
    LGKM_BAR();
    // lane-coalesced store: 16 lanes = one contiguous 256 B row segment.
    #pragma unroll
    for (int it2 = 0; it2 < 8; ++it2) {
        const int id = it2 * 256 + tid;
        const int rr = id >> 4, off = (id & 15) * 8;
        *(uint4*)(W + ((size_t)b * NN + J + rr) * NN + I + off) =
            *(const uint4*)&WtT[rr * 136 + off];
    }

    // Denom butterflies + atomics WHILE the W(J,I) store stream drains.
    #pragma unroll
    for (int i = 0; i < 4; ++i) {
        #pragma unroll
        for (int r = 0; r < 4; ++r) {
            float s = rowpart[i][r];
            s += __shfl_xor(s, 1);
            s += __shfl_xor(s, 2);
            s += __shfl_xor(s, 4);
            s += __shfl_xor(s, 8);
            if (m_ == 0)
                atomicAdd(&denom[b * NN + I + wr * 64 + i * 16 + quad * 4 + r], s);
        }
    }
    if (!diag) {
        #pragma unroll
        for (int j = 0; j < 4; ++j) {
            float s = colpart[j];
            s += __shfl_xor(s, 16);
            s += __shfl_xor(s, 32);
            if (quad == 0)
                atomicAdd(&denom[b * NN + J + wc * 64 + j * 16 + m_], s);
        }
    }

    // Phase 2 (off-diag): row-major Wt -> coalesced W(I,J).
    if (!diag) {
        LGKM_BAR();   // phase-1 LDS reads done; stores/atomics still in flight
        _Float16* Wt = smem;
        #pragma unroll
        for (int i = 0; i < 4; ++i) {
            const int rowb = wr * 64 + i * 16 + quad * 4;
            #pragma unroll
            for (int j = 0; j < 4; ++j) {
                const int col = wc * 64 + j * 16 + m_;
                #pragma unroll
                for (int r = 0; r < 4; ++r)
                    Wt[(rowb + r) * 136 + col] = wq[i][j][r];
            }
        }
        LGKM_BAR();
        #pragma unroll
        for (int it2 = 0; it2 < 8; ++it2) {
            const int id = it2 * 256 + tid;
            const int rr = id >> 4, off = (id & 15) * 8;
            *(uint4*)(W + ((size_t)b * NN + I + rr) * NN + J + off) =
                *(const uint4*)&Wt[rr * 136 + off];
        }
    }
}

// ---------------------------------------------------------------------------
// K3 (R19 exact): O = (W @ V) * (1/denom_i), fp32 out.
// 128x128 tile, 4-wave blocks, single-buffer 32.5 KiB LDS -> 4 blocks/CU,
// grid 1024 = 4 full rounds. W staging cached (L3-resident); out stores NT;
// XCD batch-pinned, 4 D-blocks of a W row-panel on adjacent same-XCD slots;
// denom load hoisted above the K-loop.
// ---------------------------------------------------------------------------
__global__ __launch_bounds__(256, 4) void k_pv(const _Float16* __restrict__ W,
                                               const _Float16* __restrict__ vT,
                                               const float* __restrict__ denom,
                                               float* __restrict__ out) {
    __shared__ _Float16 As[8192];      // [128][64]
    __shared__ _Float16 Bs[8192];      // [128][64]
    __shared__ float rdI[128];
    const int tid = threadIdx.x;
    const int lane = tid & 63, w = tid >> 6;  // 4 waves
    const int wr = w >> 1, wc = w & 1;        // 2 x 2 wave grid
    const int m_ = lane & 15, quad = lane >> 4;

    // XCD pinning: 1024 blocks, 128 slots/XCD, 2 batches/XCD.
    const int bx = blockIdx.x;
    const int xcd = bx & 7, slot = bx >> 3;        // slot 0..127
    const int b  = (slot >> 6) * 8 + xcd;          // 2 batches/XCD
    const int r_ = slot & 63;                      // 64 blocks/batch
    const int I  = (r_ >> 2) * 128;                // 16 I-tiles
    const int D0 = (r_ & 3) * 128;                 // 4 D-blocks adjacent

    // Hoisted denom load: latency hides under the entire K-loop.
    float dv = 0.f;
    if (tid < 128) dv = denom[b * NN + I + tid];

    const _Float16* Ab = W  + ((size_t)b * NN + I) * NN;
    const _Float16* Bb = vT + ((size_t)b * DD + D0) * NN;

    const int sub = lane >> 3;
    const int swc = (lane & 7) ^ sub;
    // A: 128 rows, wave stages 32 rows (4 chunks of 8). B: same.
    const _Float16* agl = Ab + (size_t)(w * 32 + sub) * NN + swc * 8;
    const _Float16* bgl = Bb + (size_t)(w * 32 + sub) * NN + swc * 8;

    f32x4 acc[4][4];
    #pragma unroll
    for (int i = 0; i < 4; ++i)
        #pragma unroll
        for (int j = 0; j < 4; ++j) acc[i][j] = (f32x4){0.f, 0.f, 0.f, 0.f};

    for (int kb = 0; kb < NN / 64; ++kb) {
        const int k0 = kb * 64;
        #pragma unroll
        for (int c = 0; c < 4; ++c) {
            async_ld16(&As[(w * 32 + c * 8) * 64], agl + (size_t)c * 8 * NN + k0);
            async_ld16(&Bs[(w * 32 + c * 8) * 64], bgl + (size_t)c * 8 * NN + k0);
        }
        VM_WAIT(0);
        RAW_BAR();
        __builtin_amdgcn_s_setprio(1);
        #pragma unroll
        for (int kc = 0; kc < 2; ++kc) {
            f16x8 af[4], bf[4];
            #pragma unroll
            for (int t = 0; t < 4; ++t) {
                const int Ra = wr * 64 + t * 16 + m_;
                const int Rb = wc * 64 + t * 16 + m_;
                af[t] = *(const f16x8*)&As[Ra * 64 + (((kc * 4 + quad) ^ (Ra & 7)) * 8)];
                bf[t] = *(const f16x8*)&Bs[Rb * 64 + (((kc * 4 + quad) ^ (Rb & 7)) * 8)];
            }
            #pragma unroll
            for (int i = 0; i < 4; ++i)
                #pragma unroll
                for (int j = 0; j < 4; ++j)
                    acc[i][j] = __builtin_amdgcn_mfma_f32_16x16x32_f16(af[i], bf[j], acc[i][j], 0, 0, 0);
        }
        __builtin_amdgcn_s_setprio(0);
        RAW_BAR();   // all waves done reading before next stage overwrites
    }

    // Epilogue: broadcast reciprocals via LDS, NT stores.
    if (tid < 128) rdI[tid] = 1.0f / dv;
    LGKM_BAR();

    #pragma unroll
    for (int i = 0; i < 4; ++i) {
        const int rowb = wr * 64 + i * 16 + quad * 4;
        #pragma unroll
        for (int r = 0; r < 4; ++r) {
            const float sc = rdI[rowb + r];
            float* op = out + ((size_t)(b * NN + I + rowb + r)) * DD + D0;
            #pragma unroll
            for (int j = 0; j < 4; ++j)
                __builtin_nontemporal_store(acc[i][j][r] * sc,
                                            op + wc * 64 + j * 16 + m_);
        }
    }
}

// ---------------------------------------------------------------------------
extern "C" void kernel_launch(void* const* d_in, const int* in_sizes, int n_in,
                              void* d_out, int out_size, void* d_ws, size_t ws_size,
                              hipStream_t stream) {
    const float* x = (const float*)d_in[0];
    char* ws = (char*)d_ws;
    _Float16* xhn   = (_Float16*)(ws);                        // 32 MiB normalized fp16
    _Float16* vT    = (_Float16*)(ws + (size_t)33554432);     // 32 MiB fp16 x^T
    _Float16* W     = (_Float16*)(ws + (size_t)67108864);     // 128 MiB fp16 exp-scores
    float*    denom = (float*)   (ws + (size_t)201326592);    // 128 KiB
    float*    out   = (float*)d_out;

    k_prep<<<dim3(NN / 64, BB), 256, 0, stream>>>(x, xhn, vT, denom);
    const int npairs = (NN / 128) * (NN / 128 + 1) / 2;   // 136
    k_scores<<<dim3(npairs, 1, BB), 256, 0, stream>>>(xhn, W, denom);
    // 1024 blocks = 4 blocks/CU (32.5 KiB LDS, 4-wave blocks), XCD batch-pinned
    k_pv<<<dim3(1024, 1, 1), 256, 0, stream>>>(W, vT, denom, out);
}

// Round 24
// 169.926 us; speedup vs baseline: 1.0069x; 1.0051x over previous
//
#include <hip/hip_runtime.h>
#include <hip/hip_bf16.h>
#include <cstdint>
#include <cstddef>

// Problem shape (fixed): x [B=16][N=2048][D=512] fp32
#define BB 16
#define NN 2048
#define DD 512

typedef _Float16 f16x8 __attribute__((ext_vector_type(8)));
typedef _Float16 f16x4 __attribute__((ext_vector_type(4)));
typedef float f32x4 __attribute__((ext_vector_type(4)));
typedef unsigned int u32x4 __attribute__((ext_vector_type(4)));

// Async global->LDS, 16 B per lane. LDS dest = wave-uniform base + lane*16.
__device__ __forceinline__ void async_ld16(void* lds, const void* g) {
    __builtin_amdgcn_global_load_lds(
        (const __attribute__((address_space(1))) unsigned int*)(uintptr_t)g,
        (__attribute__((address_space(3))) unsigned int*)(uint32_t)(uintptr_t)lds,
        16, 0, 0);
}

#define VM_WAIT(n) asm volatile("s_waitcnt vmcnt(" #n ")" ::: "memory")
#define RAW_BAR()  do { asm volatile("" ::: "memory"); __builtin_amdgcn_s_barrier(); asm volatile("" ::: "memory"); } while (0)
// LDS-order-only barrier: global stores/atomics keep draining.
#define LGKM_BAR() do { asm volatile("s_waitcnt lgkmcnt(0)" ::: "memory"); \
                        __builtin_amdgcn_s_barrier();                      \
                        __builtin_amdgcn_sched_barrier(0); } while (0)

// ---------------------------------------------------------------------------
// K1 (fused): read x ONCE (non-temporal: stream-once). Per 64-row slab:
// norms, xhn (normalized fp16), vT (fp16 transpose), denom zero-init.
// grid (NN/64, BB), 256 threads.
// ---------------------------------------------------------------------------
__global__ __launch_bounds__(256) void k_prep(const float* __restrict__ x,
                                              _Float16* __restrict__ xhn,
                                              _Float16* __restrict__ vT,
                                              float* __restrict__ denom) {
    __shared__ _Float16 t[512 * 66];     // [d][j], pitch 66 halves
    const int tid = threadIdx.x, lane = tid & 63, w = tid >> 6;
    const int b = blockIdx.y, j0 = blockIdx.x * 64;
    if (tid < 64) denom[b * NN + j0 + tid] = 0.f;
    const float* xb = x + ((size_t)b * NN + j0) * DD;

    for (int rr = 0; rr < 16; ++rr) {
        const int jj = w * 16 + rr;                 // row within slab
        const float* xr = xb + (size_t)jj * DD;
        f32x4 a = __builtin_nontemporal_load((const f32x4*)xr + lane);
        f32x4 c = __builtin_nontemporal_load((const f32x4*)xr + lane + 64);
        float ss = a[0]*a[0] + a[1]*a[1] + a[2]*a[2] + a[3]*a[3]
                 + c[0]*c[0] + c[1]*c[1] + c[2]*c[2] + c[3]*c[3];
        #pragma unroll
        for (int o = 1; o < 64; o <<= 1) ss += __shfl_xor(ss, o);
        const float rn = 1.0f / sqrtf(ss);
        // normalized fp16 row (coalesced 8B stores)
        _Float16* dst = xhn + ((size_t)b * NN + j0 + jj) * DD;
        f16x4 v0 = {(_Float16)(a[0]*rn), (_Float16)(a[1]*rn), (_Float16)(a[2]*rn), (_Float16)(a[3]*rn)};
        f16x4 v1 = {(_Float16)(c[0]*rn), (_Float16)(c[1]*rn), (_Float16)(c[2]*rn), (_Float16)(c[3]*rn)};
        *(f16x4*)(dst + 4 * lane) = v0;
        *(f16x4*)(dst + 256 + 4 * lane) = v1;
        // unnormalized fp16 into transposed LDS tile
        const int d0 = 4 * lane, d1 = 256 + 4 * lane;
        t[(d0 + 0) * 66 + jj] = (_Float16)a[0];
        t[(d0 + 1) * 66 + jj] = (_Float16)a[1];
        t[(d0 + 2) * 66 + jj] = (_Float16)a[2];
        t[(d0 + 3) * 66 + jj] = (_Float16)a[3];
        t[(d1 + 0) * 66 + jj] = (_Float16)c[0];
        t[(d1 + 1) * 66 + jj] = (_Float16)c[1];
        t[(d1 + 2) * 66 + jj] = (_Float16)c[2];
        t[(d1 + 3) * 66 + jj] = (_Float16)c[3];
    }
    LGKM_BAR();   // xhn global stores keep draining under the vT phase
    // store vT rows: 512 d x 8 chunks of 8 halves; 4B-aligned b32 LDS reads.
    #pragma unroll
    for (int it = 0; it < 16; ++it) {
        const int id = it * 256 + tid;
        const int d = id >> 3, ch = (id & 7) * 8;
        const uint32_t* tp = (const uint32_t*)&t[d * 66 + ch];
        uint4 v = {tp[0], tp[1], tp[2], tp[3]};
        *(uint4*)(vT + ((size_t)b * DD + d) * NN + j0 + ch) = v;
    }
}

// ---------------------------------------------------------------------------
// K2: W = exp( xhn xhn^T ), symmetric-triangular. 128x128 block, 4 waves.
// BK=32 RING-2 double buffer (2 x 16 KiB), counted vmcnt(4) (R22: -2.5 us).
// NEW this round: read/stage swizzle involution f(R) = (R>>1)&3 (was R&3).
// With 64 B rows, bank-set = (row parity, 16B chunk) = 8 sets for 16 lanes;
// f=(R>>1)&3 maps each parity group 2-to-1 onto the 4 chunks -> exactly
// 2-way aliasing (free, m136) instead of 4-way. Both sides use the same
// involution: stage source chunk sck^f(row) at LDS slot sck; read slot
// quad^f(R) -> recovers K-chunk quad.
// Epilogue: stores-before-atomics, LGKM-only barriers, lane-coalesced stores.
// ---------------------------------------------------------------------------
__global__ __launch_bounds__(256, 4) void k_scores(const _Float16* __restrict__ xhn,
                                                   _Float16* __restrict__ W,
                                                   float* __restrict__ denom) {
    __shared__ _Float16 smem[17408];          // 2 x 8192 GEMM bufs; epi: 128x136
    const int tid = threadIdx.x;
    const int lane = tid & 63, wv = tid >> 6;
    const int wr = wv >> 1, wc = wv & 1;
    const int m_ = lane & 15, quad = lane >> 4;
    const int b = blockIdx.z;

    // XCD swizzle: 136 = 8 * 17 -> each XCD gets 17 consecutive pairs.
    const int swz = (blockIdx.x % 8) * 17 + blockIdx.x / 8;
    int rem = swz, ti = 0, rowlen = NN / 128;
    while (rem >= rowlen) { rem -= rowlen; ++ti; --rowlen; }
    const int tj = ti + rem;
    const int I = ti * 128, J = tj * 128;
    const bool diag = (ti == tj);

    const _Float16* Ab = xhn + ((size_t)b * NN + I) * DD;
    const _Float16* Bb = xhn + ((size_t)b * NN + J) * DD;

    f32x4 acc[4][4];
    #pragma unroll
    for (int i = 0; i < 4; ++i)
        #pragma unroll
        for (int j = 0; j < 4; ++j) acc[i][j] = (f32x4){0.f, 0.f, 0.f, 0.f};

    // Staging geometry (BK=32, 64 B rows): lane covers row wv*16 + (lane>>2),
    // 16B chunk lane&3; source chunk pre-swizzled by f(row)=(row>>1)&3
    // (both-sides involution; wave-group offset wv*16 divides out mod 4
    // after >>1: (wv*16)>>1 = wv*8, &3 = 0).
    const int srw = lane >> 2;                // row within 16-row wave group
    const int sck = lane & 3;                 // 16B chunk
    const int soff = ((sck ^ ((srw >> 1) & 3)) * 8);   // halves
    const _Float16* agl = Ab + (size_t)(wv * 16 + srw) * DD + soff;
    const _Float16* bgl = Bb + (size_t)(wv * 16 + srw) * DD + soff;

// Stage tile kb_ (4 vmem loads: A rows 0-63, A rows 64-127, B same).
#define S_STG(kb_) do {                                                       \
    _Float16* A_ = smem + (((kb_) & 1) << 13);   /* buf = kb&1, 8192 halves */\
    const int k0_ = (kb_) * 32;                                               \
    async_ld16(&A_[(wv * 16) * 32],             agl + k0_);                   \
    async_ld16(&A_[(64 + wv * 16) * 32],        agl + (size_t)64 * DD + k0_); \
    async_ld16(&A_[4096 + (wv * 16) * 32],      bgl + k0_);                   \
    async_ld16(&A_[4096 + (64 + wv * 16) * 32], bgl + (size_t)64 * DD + k0_); \
    } while (0)

    S_STG(0); S_STG(1);
    for (int kb = 0; kb < DD / 32; ++kb) {
        if (kb == DD / 32 - 1) { VM_WAIT(0); } else { VM_WAIT(4); }
        RAW_BAR();
        const _Float16* As_ = smem + ((kb & 1) << 13);
        const _Float16* Bs_ = As_ + 4096;
        __builtin_amdgcn_s_setprio(1);
        {
            f16x8 af[4], bf[4];
            #pragma unroll
            for (int t = 0; t < 4; ++t) {
                const int Ra = wr * 64 + t * 16 + m_;
                const int Rb = wc * 64 + t * 16 + m_;
                af[t] = *(const f16x8*)&As_[Ra * 32 + ((quad ^ ((Ra >> 1) & 3)) * 8)];
                bf[t] = *(const f16x8*)&Bs_[Rb * 32 + ((quad ^ ((Rb >> 1) & 3)) * 8)];
            }
            #pragma unroll
            for (int i = 0; i < 4; ++i)
                #pragma unroll
                for (int j = 0; j < 4; ++j)
                    acc[i][j] = __builtin_amdgcn_mfma_f32_16x16x32_f16(af[i], bf[j], acc[i][j], 0, 0, 0);
        }
        __builtin_amdgcn_s_setprio(0);
        RAW_BAR();   // all waves done reading buf before stage(kb+2) overwrites
        if (kb + 2 < DD / 32) S_STG(kb + 2);
    }
#undef S_STG

    // Epilogue: exp into packed f16x4; register row/col partial sums.
    f16x4 wq[4][4];
    float rowpart[4][4];
    float colpart[4] = {0.f, 0.f, 0.f, 0.f};
    #pragma unroll
    for (int i = 0; i < 4; ++i)
        #pragma unroll
        for (int r = 0; r < 4; ++r) rowpart[i][r] = 0.f;

    #pragma unroll
    for (int i = 0; i < 4; ++i) {
        #pragma unroll
        for (int j = 0; j < 4; ++j) {
            #pragma unroll
            for (int r = 0; r < 4; ++r) {
                const float w = __expf(acc[i][j][r]);
                wq[i][j][r] = (_Float16)w;
                rowpart[i][r] += w;
                colpart[j] += w;
            }
        }
    }

    // Phase 1 FIRST: WtT[col][row] (stride 136) -> coalesced W(J,I) stores.
    _Float16* WtT = smem;
    #pragma unroll
    for (int i = 0; i < 4; ++i) {
        const int rowb = wr * 64 + i * 16 + quad * 4;
        #pragma unroll
        for (int j = 0; j < 4; ++j) {
            const int col = wc * 64 + j * 16 + m_;
            *(f16x4*)&WtT[col * 136 + rowb] = wq[i][j];
        }
    }
    LGKM_BAR();
    // lane-coalesced store: 16 lanes = one contiguous 256 B row segment.
    #pragma unroll
    for (int it2 = 0; it2 < 8; ++it2) {
        const int id = it2 * 256 + tid;
        const int rr = id >> 4, off = (id & 15) * 8;
        *(uint4*)(W + ((size_t)b * NN + J + rr) * NN + I + off) =
            *(const uint4*)&WtT[rr * 136 + off];
    }

    // Denom butterflies + atomics WHILE the W(J,I) store stream drains.
    #pragma unroll
    for (int i = 0; i < 4; ++i) {
        #pragma unroll
        for (int r = 0; r < 4; ++r) {
            float s = rowpart[i][r];
            s += __shfl_xor(s, 1);
            s += __shfl_xor(s, 2);
            s += __shfl_xor(s, 4);
            s += __shfl_xor(s, 8);
            if (m_ == 0)
                atomicAdd(&denom[b * NN + I + wr * 64 + i * 16 + quad * 4 + r], s);
        }
    }
    if (!diag) {
        #pragma unroll
        for (int j = 0; j < 4; ++j) {
            float s = colpart[j];
            s += __shfl_xor(s, 16);
            s += __shfl_xor(s, 32);
            if (quad == 0)
                atomicAdd(&denom[b * NN + J + wc * 64 + j * 16 + m_], s);
        }
    }

    // Phase 2 (off-diag): row-major Wt -> coalesced W(I,J).
    if (!diag) {
        LGKM_BAR();   // phase-1 LDS reads done; stores/atomics still in flight
        _Float16* Wt = smem;
        #pragma unroll
        for (int i = 0; i < 4; ++i) {
            const int rowb = wr * 64 + i * 16 + quad * 4;
            #pragma unroll
            for (int j = 0; j < 4; ++j) {
                const int col = wc * 64 + j * 16 + m_;
                #pragma unroll
                for (int r = 0; r < 4; ++r)
                    Wt[(rowb + r) * 136 + col] = wq[i][j][r];
            }
        }
        LGKM_BAR();
        #pragma unroll
        for (int it2 = 0; it2 < 8; ++it2) {
            const int id = it2 * 256 + tid;
            const int rr = id >> 4, off = (id & 15) * 8;
            *(uint4*)(W + ((size_t)b * NN + I + rr) * NN + J + off) =
                *(const uint4*)&Wt[rr * 136 + off];
        }
    }
}

// ---------------------------------------------------------------------------
// K3 (R19 exact): O = (W @ V) * (1/denom_i), fp32 out.
// 128x128 tile, 4-wave blocks, single-buffer 32.5 KiB LDS -> 4 blocks/CU,
// grid 1024 = 4 full rounds. W staging cached (L3-resident); out stores NT;
// XCD batch-pinned, 4 D-blocks of a W row-panel on adjacent same-XCD slots;
// denom load hoisted above the K-loop.
// ---------------------------------------------------------------------------
__global__ __launch_bounds__(256, 4) void k_pv(const _Float16* __restrict__ W,
                                               const _Float16* __restrict__ vT,
                                               const float* __restrict__ denom,
                                               float* __restrict__ out) {
    __shared__ _Float16 As[8192];      // [128][64]
    __shared__ _Float16 Bs[8192];      // [128][64]
    __shared__ float rdI[128];
    const int tid = threadIdx.x;
    const int lane = tid & 63, w = tid >> 6;  // 4 waves
    const int wr = w >> 1, wc = w & 1;        // 2 x 2 wave grid
    const int m_ = lane & 15, quad = lane >> 4;

    // XCD pinning: 1024 blocks, 128 slots/XCD, 2 batches/XCD.
    const int bx = blockIdx.x;
    const int xcd = bx & 7, slot = bx >> 3;        // slot 0..127
    const int b  = (slot >> 6) * 8 + xcd;          // 2 batches/XCD
    const int r_ = slot & 63;                      // 64 blocks/batch
    const int I  = (r_ >> 2) * 128;                // 16 I-tiles
    const int D0 = (r_ & 3) * 128;                 // 4 D-blocks adjacent

    // Hoisted denom load: latency hides under the entire K-loop.
    float dv = 0.f;
    if (tid < 128) dv = denom[b * NN + I + tid];

    const _Float16* Ab = W  + ((size_t)b * NN + I) * NN;
    const _Float16* Bb = vT + ((size_t)b * DD + D0) * NN;

    const int sub = lane >> 3;
    const int swc = (lane & 7) ^ sub;
    // A: 128 rows, wave stages 32 rows (4 chunks of 8). B: same.
    const _Float16* agl = Ab + (size_t)(w * 32 + sub) * NN + swc * 8;
    const _Float16* bgl = Bb + (size_t)(w * 32 + sub) * NN + swc * 8;

    f32x4 acc[4][4];
    #pragma unroll
    for (int i = 0; i < 4; ++i)
        #pragma unroll
        for (int j = 0; j < 4; ++j) acc[i][j] = (f32x4){0.f, 0.f, 0.f, 0.f};

    for (int kb = 0; kb < NN / 64; ++kb) {
        const int k0 = kb * 64;
        #pragma unroll
        for (int c = 0; c < 4; ++c) {
            async_ld16(&As[(w * 32 + c * 8) * 64], agl + (size_t)c * 8 * NN + k0);
            async_ld16(&Bs[(w * 32 + c * 8) * 64], bgl + (size_t)c * 8 * NN + k0);
        }
        VM_WAIT(0);
        RAW_BAR();
        __builtin_amdgcn_s_setprio(1);
        #pragma unroll
        for (int kc = 0; kc < 2; ++kc) {
            f16x8 af[4], bf[4];
            #pragma unroll
            for (int t = 0; t < 4; ++t) {
                const int Ra = wr * 64 + t * 16 + m_;
                const int Rb = wc * 64 + t * 16 + m_;
                af[t] = *(const f16x8*)&As[Ra * 64 + (((kc * 4 + quad) ^ (Ra & 7)) * 8)];
                bf[t] = *(const f16x8*)&Bs[Rb * 64 + (((kc * 4 + quad) ^ (Rb & 7)) * 8)];
            }
            #pragma unroll
            for (int i = 0; i < 4; ++i)
                #pragma unroll
                for (int j = 0; j < 4; ++j)
                    acc[i][j] = __builtin_amdgcn_mfma_f32_16x16x32_f16(af[i], bf[j], acc[i][j], 0, 0, 0);
        }
        __builtin_amdgcn_s_setprio(0);
        RAW_BAR();   // all waves done reading before next stage overwrites
    }

    // Epilogue: broadcast reciprocals via LDS, NT stores.
    if (tid < 128) rdI[tid] = 1.0f / dv;
    LGKM_BAR();

    #pragma unroll
    for (int i = 0; i < 4; ++i) {
        const int rowb = wr * 64 + i * 16 + quad * 4;
        #pragma unroll
        for (int r = 0; r < 4; ++r) {
            const float sc = rdI[rowb + r];
            float* op = out + ((size_t)(b * NN + I + rowb + r)) * DD + D0;
            #pragma unroll
            for (int j = 0; j < 4; ++j)
                __builtin_nontemporal_store(acc[i][j][r] * sc,
                                            op + wc * 64 + j * 16 + m_);
        }
    }
}

// ---------------------------------------------------------------------------
extern "C" void kernel_launch(void* const* d_in, const int* in_sizes, int n_in,
                              void* d_out, int out_size, void* d_ws, size_t ws_size,
                              hipStream_t stream) {
    const float* x = (const float*)d_in[0];
    char* ws = (char*)d_ws;
    _Float16* xhn   = (_Float16*)(ws);                        // 32 MiB normalized fp16
    _Float16* vT    = (_Float16*)(ws + (size_t)33554432);     // 32 MiB fp16 x^T
    _Float16* W     = (_Float16*)(ws + (size_t)67108864);     // 128 MiB fp16 exp-scores
    float*    denom = (float*)   (ws + (size_t)201326592);    // 128 KiB
    float*    out   = (float*)d_out;

    k_prep<<<dim3(NN / 64, BB), 256, 0, stream>>>(x, xhn, vT, denom);
    const int npairs = (NN / 128) * (NN / 128 + 1) / 2;   // 136
    k_scores<<<dim3(npairs, 1, BB), 256, 0, stream>>>(xhn, W, denom);
    // 1024 blocks = 4 blocks/CU (32.5 KiB LDS, 4-wave blocks), XCD batch-pinned
    k_pv<<<dim3(1024, 1, 1), 256, 0, stream>>>(W, vT, denom, out);
}